// Round 5
// baseline (275.759 us; speedup 1.0000x reference)
//
#include <hip/hip_runtime.h>

// Gridding: B batches of N float3 points -> per-batch 64^3 grid of trilinear
// scatter weights.
//
// R9 (3rd submit; R3/R4 benches were infra failures — no counters, kernel
// audited for hang/fault modes: all LDS/global indices bounded, no barriers
// in divergent flow, static LDS below R8's verified 155648 B).
// R8 was DS-pipe-bound (~271K cyc/CU = atomics 176K + queue-writes 74K +
// misc 21K; law ~1.8 cyc per ACTIVE-lane atomic). Attack both DS terms:
//  - FOUR parity grids (offsets (0,0),(0,1),(1,0),(1,1) in (y,z)): every
//    2x2 quad is tile-aligned in grid g=(iy&1)*2+(iz&1), tile (iy>>1,iz>>1)
//    for ALL grids -> EXACTLY 2 u64 atomics per point (1 per x-plane),
//    branchless heavy body (no 3-way parity divergence). 16.8M lane-atomics
//    (was 25M).
//  - LDS cost: 4 grids x TH x 8 KB -> needs TH=4 (128 KB), NSLAB=16. Scan
//    visits double, so the queue is slimmed to POINT INDICES (u32): push is
//    one ds_write_b32 (was 3), drain re-gathers the 12 B from global (VMEM
//    pipe, L2/LLC-resident via b%8 XCD affinity; linear_blk = b+32k == b%8).
//  - DS ledger: atomics 118K + qwrite 49K + misc 21K ~ 188K cyc ~ 78 us.
//  - Output is BIT-IDENTICAL to R8: same per-corner quantization, integer
//    cell sums merely split across parity grids and re-summed in decode.
//  - LDS 131072 + 8192 = 139264 B. Grid (B,16) = 512 wgs -> 2 rounds/CU.

#define GS    64
#define G2    (GS * GS)          // 4096
#define G3    (GS * GS * GS)     // 262144
#define SHALF 32                 // scale (half-extent)
#define TH    4                  // planes per slab
#define NSLAB (GS / TH)          // 16
#define TPB   1024
#define NWAVE (TPB / 64)         // 16
#define QCAP  128                // per-wave queue capacity (u32 indices)
#define NGW   (4 * TH * 1024)    // u64 words: 4 parity grids x TH x 1024 tiles

#define QSF   1024.0f            // weight quantization scale (2^10)
#define QDEC  (1.0f / 1024.0f)

typedef unsigned long long ull;

__device__ __forceinline__ ull pack4(unsigned q00, unsigned q01,
                                     unsigned q10, unsigned q11) {
    // field f = dy*2+dz at bits [16f, 16f+16)
    return (ull)q00 | ((ull)q01 << 16) | ((ull)q10 << 32) | ((ull)q11 << 48);
}

// Heavy body: re-gather point, weights, quantize, 2 packed LDS atomics.
// Precondition: point passed rel-range and zero-mask checks.
__device__ __forceinline__ void heavy(int idx, const float* __restrict__ ptb,
                                      int k, ull* __restrict__ g64) {
    const float* pp = ptb + 3 * (size_t)idx;
    float x = pp[0] * (float)SHALF;
    float y = pp[1] * (float)SHALF;
    float z = pp[2] * (float)SHALF;

    float lx = floorf(x), ly = floorf(y), lz = floorf(z);
    int ix = min(max((int)lx + SHALF, 0), GS - 2);
    int iy = min(max((int)ly + SHALF, 0), GS - 2);
    int iz = min(max((int)lz + SHALF, 0), GS - 2);
    int rel = ix - TH * k;

    float fx = x - lx, fy = y - ly, fz = z - lz;
    float wx0 = (1.0f - fx) * ((rel >= 0)      ? 1.0f : 0.0f);
    float wx1 = fx          * ((rel <= TH - 2) ? 1.0f : 0.0f);
    int plo = max(rel, 0);
    int phi = min(rel + 1, TH - 1);

    float wy0 = 1.0f - fy, wy1 = fy;
    float wz0 = 1.0f - fz, wz1 = fz;
    float a00 = wx0 * wy0, a01 = wx0 * wy1;
    float b00 = wx1 * wy0, b01 = wx1 * wy1;

    // quantize (round-half-up; all weights >= 0). q[plane][dy][dz]
    unsigned qa00z0 = (unsigned)(a00 * wz0 * QSF + 0.5f);
    unsigned qa00z1 = (unsigned)(a00 * wz1 * QSF + 0.5f);
    unsigned qa01z0 = (unsigned)(a01 * wz0 * QSF + 0.5f);
    unsigned qa01z1 = (unsigned)(a01 * wz1 * QSF + 0.5f);
    unsigned qb00z0 = (unsigned)(b00 * wz0 * QSF + 0.5f);
    unsigned qb00z1 = (unsigned)(b00 * wz1 * QSF + 0.5f);
    unsigned qb01z0 = (unsigned)(b01 * wz0 * QSF + 0.5f);
    unsigned qb01z1 = (unsigned)(b01 * wz1 * QSF + 0.5f);

    // parity grid: quad (iy..iy+1, iz..iz+1) is tile-aligned in grid g
    const int g = ((iy & 1) << 1) | (iz & 1);
    const int t = ((iy >> 1) << 5) + (iz >> 1);        // tile within plane

    ull va = pack4(qa00z0, qa00z1, qa01z0, qa01z1);
    ull vb = pack4(qb00z0, qb00z1, qb01z0, qb01z1);
    if (va) atomicAdd(&g64[((g * TH + plo) << 10) + t], va);
    if (vb) atomicAdd(&g64[((g * TH + phi) << 10) + t], vb);
}

// cheap test + ballot-compacted index push; drains 64 at full occupancy
__device__ __forceinline__ void push_pt(float px, float py, float pz, int idx,
                                        int k, int lane,
                                        unsigned* __restrict__ q, int& qn,
                                        const float* __restrict__ ptb,
                                        ull* __restrict__ g64) {
    float x = px * (float)SHALF;
    float lx = floorf(x);
    int   ix  = min(max((int)lx + SHALF, 0), GS - 2);
    int   rel = ix - TH * k;
    // raw-sum test == scaled-sum test: *32 is a power-of-2 (exact in fp32)
    bool pass = ((unsigned)(rel + 1) <= (unsigned)TH) &&
                ((px + py + pz) != 0.0f);
    ull m = __ballot(pass);
    if (pass) {
        q[qn + (int)__popcll(m & ((1ull << lane) - 1))] = (unsigned)idx;
    }
    qn += (int)__popcll(m);          // wave-uniform
    if (qn >= 64) {                  // wave-uniform branch
        qn -= 64;
        heavy((int)q[qn + lane], ptb, k, g64);
    }
}

__global__ __launch_bounds__(TPB, 1) void gridding_u16_kernel(
    const float* __restrict__ pt, float* __restrict__ out, int N) {
    __shared__ ull      g64[NGW];             // 128 KB: 4 parity grids
    __shared__ unsigned qidx[NWAVE * QCAP];   // 8 KB: per-wave index queues

    const int b    = blockIdx.x;   // batch (b%8 XCD affinity: linear=b+32k)
    const int k    = blockIdx.y;   // slab (4 planes)
    const int tid  = threadIdx.x;
    const int wid  = tid >> 6;
    const int lane = tid & 63;

    for (int t = tid; t < NGW; t += TPB) g64[t] = 0ull;
    __syncthreads();

    const float*  ptb = pt + (size_t)b * N * 3;
    const float4* p4  = (const float4*)ptb;
    unsigned* q  = qidx + wid * QCAP;
    int       qn = 0;

    const int nq    = N >> 2;          // 4-point quads
    const int niter = nq / TPB;        // exact (launcher guards N%(4*TPB)==0)

    for (int it = 0; it < niter; ++it) {
        int qd = it * TPB + tid;
        float4 A = p4[3 * qd + 0], Bv = p4[3 * qd + 1], C = p4[3 * qd + 2];
        int i0 = qd << 2;
        push_pt(A.x,  A.y,  A.z,  i0,     k, lane, q, qn, ptb, g64);
        push_pt(A.w,  Bv.x, Bv.y, i0 + 1, k, lane, q, qn, ptb, g64);
        push_pt(Bv.z, Bv.w, C.x,  i0 + 2, k, lane, q, qn, ptb, g64);
        push_pt(C.y,  C.z,  C.w,  i0 + 3, k, lane, q, qn, ptb, g64);
    }
    // tail drain (qn in [0,63], wave-uniform)
    if (lane < qn) heavy((int)q[lane], ptb, k, g64);
    __syncthreads();

    // decode: cell (pl,y,z) = sum over parity grids g=(gy,gz) of the u16 at
    // tile ((y-gy)>>1,(z-gz)>>1), field ((y-gy)&1)*2+((z-gz)&1); grid (gy,gz)
    // has no tile containing y<gy or z<gz (those cells get no writes there).
    const unsigned short* g16 = (const unsigned short*)g64;
    float* ob = out + (size_t)b * G3 + (size_t)(TH * k) * G2;
    for (int t = tid; t < TH * G2; t += TPB) {
        int pl = t >> 12;
        int cell = t & 4095;
        int y = cell >> 6, z = cell & 63;
        unsigned v = 0;
#pragma unroll
        for (int gy = 0; gy < 2; ++gy) {
#pragma unroll
            for (int gz = 0; gz < 2; ++gz) {
                if (y >= gy && z >= gz) {
                    int my = (y - gy) >> 1, mz = (z - gz) >> 1;
                    int f  = (((y - gy) & 1) << 1) | ((z - gz) & 1);
                    int g  = (gy << 1) | gz;
                    v += g16[((((g * TH + pl) << 10) + (my << 5) + mz) << 2) + f];
                }
            }
        }
        ob[t] = (float)v * QDEC;
    }
}

// ---- fallback (general shapes): R1 atomic kernel ----
__global__ void gridding_atomic_kernel(const float* __restrict__ pt,
                                       float* __restrict__ out, int P, int N) {
    int i = blockIdx.x * blockDim.x + threadIdx.x;
    if (i >= P) return;
    int b = i / N;
    float x = pt[3 * i + 0] * (float)SHALF;
    float y = pt[3 * i + 1] * (float)SHALF;
    float z = pt[3 * i + 2] * (float)SHALF;
    const float m = ((x + y + z) != 0.0f) ? 1.0f : 0.0f;
    float lx = floorf(x), ly = floorf(y), lz = floorf(z);
    float fx = x - lx, fy = y - ly, fz = z - lz;
    int ix = min(max((int)lx + SHALF, 0), GS - 2);
    int iy = min(max((int)ly + SHALF, 0), GS - 2);
    int iz = min(max((int)lz + SHALF, 0), GS - 2);
    float* base = out + (size_t)b * G3 + ((ix * GS + iy) * GS + iz);
    float wx0 = (1.0f - fx) * m, wx1 = fx * m;
    float w00 = wx0 * (1.0f - fy), w01 = wx0 * fy;
    float w10 = wx1 * (1.0f - fy), w11 = wx1 * fy;
    atomicAdd(base,               w00 * (1.0f - fz));
    atomicAdd(base + 1,           w00 * fz);
    atomicAdd(base + GS,          w01 * (1.0f - fz));
    atomicAdd(base + GS + 1,      w01 * fz);
    atomicAdd(base + G2,          w10 * (1.0f - fz));
    atomicAdd(base + G2 + 1,      w10 * fz);
    atomicAdd(base + G2 + GS,     w11 * (1.0f - fz));
    atomicAdd(base + G2 + GS + 1, w11 * fz);
}

extern "C" void kernel_launch(void* const* d_in, const int* in_sizes, int n_in,
                              void* d_out, int out_size, void* d_ws, size_t ws_size,
                              hipStream_t stream) {
    const float* pt  = (const float*)d_in[0];
    float*       out = (float*)d_out;

    const int P = in_sizes[0] / 3;       // total points (B*N)
    const int B = out_size / G3;         // 32
    const int N = (B > 0) ? P / B : 0;   // 262144

    const bool fast = (B > 0) && (out_size == B * G3) && (P == B * N) &&
                      (N % (4 * TPB) == 0);

    if (fast) {
        dim3 g(B, NSLAB);                // 512 wgs (2 rounds over 256 CUs)
        gridding_u16_kernel<<<g, TPB, 0, stream>>>(pt, out, N);
    } else {
        hipMemsetAsync(d_out, 0, (size_t)out_size * sizeof(float), stream);
        gridding_atomic_kernel<<<(P + 255) / 256, 256, 0, stream>>>(pt, out, P, N);
    }
}

// Round 6
// 226.502 us; speedup vs baseline: 1.2175x; 1.2175x over previous
//
#include <hip/hip_runtime.h>

// Gridding: B batches of N float3 points -> per-batch 64^3 grid of trilinear
// scatter weights.
//
// R10: R9 post-mortem: DS dropped as designed but runtime regressed to 172 us
// — ~150K cyc/SIMD of stall from the drain's re-gather chain (ds_read idx ->
// 3 scattered global loads at 200-600 cyc; FETCH doubled: 4 batches x 3 MB
// thrash a 4 MB XCD-L2), plus TH=4 doubled the scan VALU. Revert to the
// verified R8 structure (TH=8, 8 slabs, 2-grid 2x2-tile parity scatter,
// DS-saturated at 271K cyc/CU) and change ONE thing:
//  - Queue entry = ONE u64 with 3x21-bit fixed-point coords (s6.15:
//    q = coord*2^20 + 2^20, truncating; decode q*2^-15 - 32 is EXACT fp32).
//    Push: 1 ds_write_b64 (was 3 ds_write_b32, 74K cyc/CU -> ~29K).
//    Drain: 1 ds_read_b64, NO VMEM on the critical path.
//  - Quantization moves each coord by < 2^-15 -> weights move by < 2^-15,
//    invisible at QSF=1024 (trilinear is continuous). Only hazard: floor-flip
//    at integer boundaries can shift rel to -2 or 8 -> drain re-tests the
//    rel-range and returns (the writes it drops have weight < 2^-15 -> 0).
//  - DS ledger: atomics 177K + qwrite 29K + qread 4K + misc 15K ~ 225K cyc
//    ~ 94 us. VALU ~97K cyc ~ 40 us (hidden).
//  - LDS: 2 x 64 KB grids + 16 waves x 128 x 8 B queue = 147456 B, 1 blk/CU.

#define GS    64
#define G2    (GS * GS)          // 4096
#define G3    (GS * GS * GS)     // 262144
#define SHALF 32                 // scale (half-extent)
#define TH    8                  // planes per slab
#define NSLAB (GS / TH)          // 8
#define TPB   1024
#define NWG   (TH * 1024)        // u64 words per grid (8 planes x 1024 tiles)
#define NWAVE (TPB / 64)         // 16
#define QCAP  128                // per-wave queue capacity (u64 entries)

#define QSF   1024.0f            // weight quantization scale (2^10)
#define QDEC  (1.0f / 1024.0f)
#define PKS   1048576.0f         // 2^20: pack scale/offset
#define UPK   (1.0f / 32768.0f)  // 2^-15: unpack scale

typedef unsigned long long ull;

__device__ __forceinline__ ull pack4(unsigned q00, unsigned q01,
                                     unsigned q10, unsigned q11) {
    // field f = dy*2+dz at bits [16f, 16f+16)
    return (ull)q00 | ((ull)q01 << 16) | ((ull)q10 << 32) | ((ull)q11 << 48);
}

// Heavy body: unpack coords, weights, quantize, dual-grid packed LDS atomics.
__device__ __forceinline__ void heavy(ull e, int k,
                                      ull* __restrict__ A64,
                                      ull* __restrict__ B64) {
    // decode 21-bit fields; values are exact multiples of 2^-15 in [-32,32)
    float x = (float)(int)(unsigned)(e & 0x1FFFFF)         * UPK - 32.0f;
    float y = (float)(int)(unsigned)((e >> 21) & 0x1FFFFF) * UPK - 32.0f;
    float z = (float)(int)(unsigned)((e >> 42) & 0x1FFFFF) * UPK - 32.0f;

    float lx = floorf(x), ly = floorf(y), lz = floorf(z);
    int ix = min(max((int)lx + SHALF, 0), GS - 2);
    int iy = min(max((int)ly + SHALF, 0), GS - 2);
    int iz = min(max((int)lz + SHALF, 0), GS - 2);
    int rel = ix - TH * k;
    // quantization can flip floor at integer boundaries (rel -> -2 or 8);
    // those writes carry weight < 2^-15 -> drop (they belong to the slab
    // that also queued this point, where it decodes consistently).
    if ((unsigned)(rel + 1) > TH) return;

    float fx = x - lx, fy = y - ly, fz = z - lz;
    float wx0 = (1.0f - fx) * ((rel >= 0)      ? 1.0f : 0.0f);
    float wx1 = fx          * ((rel <= TH - 2) ? 1.0f : 0.0f);
    int plo = max(rel, 0);
    int phi = min(rel + 1, TH - 1);

    float wy0 = 1.0f - fy, wy1 = fy;
    float wz0 = 1.0f - fz, wz1 = fz;
    float a00 = wx0 * wy0, a01 = wx0 * wy1;
    float b00 = wx1 * wy0, b01 = wx1 * wy1;

    // quantize (round-half-up; all weights >= 0). q[plane][dy][dz]
    unsigned qa00z0 = (unsigned)(a00 * wz0 * QSF + 0.5f);
    unsigned qa00z1 = (unsigned)(a00 * wz1 * QSF + 0.5f);
    unsigned qa01z0 = (unsigned)(a01 * wz0 * QSF + 0.5f);
    unsigned qa01z1 = (unsigned)(a01 * wz1 * QSF + 0.5f);
    unsigned qb00z0 = (unsigned)(b00 * wz0 * QSF + 0.5f);
    unsigned qb00z1 = (unsigned)(b00 * wz1 * QSF + 0.5f);
    unsigned qb01z0 = (unsigned)(b01 * wz0 * QSF + 0.5f);
    unsigned qb01z1 = (unsigned)(b01 * wz1 * QSF + 0.5f);

    const int t0  = (iy >> 1) * 32 + (iz >> 1);  // tile word within plane
    const int wlo = plo * 1024 + t0;
    const int whi = phi * 1024 + t0;
    const int dy = iy & 1, dz = iz & 1;

    if (dy == dz) {
        // whole 2x2 quad lives in one tile of A (even,even) or B (odd,odd)
        ull* g = dy ? B64 : A64;
        ull va = pack4(qa00z0, qa00z1, qa01z0, qa01z1);
        ull vb = pack4(qb00z0, qb00z1, qb01z0, qb01z1);
        if (va) atomicAdd(&g[wlo], va);
        if (vb) atomicAdd(&g[whi], vb);
    } else if (dz) {
        // iy even, iz odd: z-straddle in A -> tiles t0 (fields 1,3), t0+1 (0,2)
        ull va1 = ((ull)qa00z0 << 16) | ((ull)qa01z0 << 48);
        ull va2 = ((ull)qa00z1)       | ((ull)qa01z1 << 32);
        ull vb1 = ((ull)qb00z0 << 16) | ((ull)qb01z0 << 48);
        ull vb2 = ((ull)qb00z1)       | ((ull)qb01z1 << 32);
        if (va1) atomicAdd(&A64[wlo],     va1);
        if (va2) atomicAdd(&A64[wlo + 1], va2);
        if (vb1) atomicAdd(&A64[whi],     vb1);
        if (vb2) atomicAdd(&A64[whi + 1], vb2);
    } else {
        // iy odd, iz even: y-straddle in A -> tiles t0 (fields 2,3), t0+32 (0,1)
        ull va1 = ((ull)qa00z0 << 32) | ((ull)qa00z1 << 48);
        ull va2 = ((ull)qa01z0)       | ((ull)qa01z1 << 16);
        ull vb1 = ((ull)qb00z0 << 32) | ((ull)qb00z1 << 48);
        ull vb2 = ((ull)qb01z0)       | ((ull)qb01z1 << 16);
        if (va1) atomicAdd(&A64[wlo],      va1);
        if (va2) atomicAdd(&A64[wlo + 32], va2);
        if (vb1) atomicAdd(&A64[whi],      vb1);
        if (vb2) atomicAdd(&A64[whi + 32], vb2);
    }
}

// cheap test + ballot-compacted packed push; drains 64 at full occupancy
__device__ __forceinline__ void push_pt(float px, float py, float pz, int k,
                                        int lane, ull* __restrict__ q, int& qn,
                                        ull* __restrict__ A64,
                                        ull* __restrict__ B64) {
    float x = px * (float)SHALF;
    float lx = floorf(x);
    int   ix  = min(max((int)lx + SHALF, 0), GS - 2);
    int   rel = ix - TH * k;
    // raw-sum test == scaled-sum test: *32 is a power-of-2 (exact in fp32)
    bool pass = ((unsigned)(rel + 1) <= (unsigned)TH) &&
                ((px + py + pz) != 0.0f);
    ull m = __ballot(pass);
    if (pass) {
        // pack coord c as (c*32 + 32)*2^15 = c*2^20 + 2^20, trunc to 21 bits
        unsigned qx = (unsigned)fmaf(px, PKS, PKS);
        unsigned qy = (unsigned)fmaf(py, PKS, PKS);
        unsigned qz = (unsigned)fmaf(pz, PKS, PKS);
        ull e = (ull)qx | ((ull)qy << 21) | ((ull)qz << 42);
        q[qn + (int)__popcll(m & ((1ull << lane) - 1))] = e;
    }
    qn += (int)__popcll(m);          // wave-uniform
    if (qn >= 64) {                  // wave-uniform branch
        qn -= 64;
        heavy(q[qn + lane], k, A64, B64);
    }
}

__global__ __launch_bounds__(TPB, 1) void gridding_u16_kernel(
    const float* __restrict__ pt, float* __restrict__ out, int N) {
    __shared__ ull A64[NWG];             // 64 KB: even-aligned 2x2 tiles
    __shared__ ull B64[NWG];             // 64 KB: (1,1)-offset tiles
    __shared__ ull qe[NWAVE * QCAP];     // 16 KB: per-wave packed queues

    const int b    = blockIdx.x;   // batch (b%8 XCD affinity)
    const int k    = blockIdx.y;   // slab (8 planes)
    const int tid  = threadIdx.x;
    const int wid  = tid >> 6;
    const int lane = tid & 63;

    for (int t = tid; t < NWG; t += TPB) { A64[t] = 0ull; B64[t] = 0ull; }
    __syncthreads();

    const float4* p4 = (const float4*)(pt + (size_t)b * N * 3);
    ull* q  = qe + wid * QCAP;
    int  qn = 0;

    const int nq    = N >> 2;          // 4-point quads
    const int niter = nq / TPB;        // exact (launcher guards N%(4*TPB)==0)

    for (int it = 0; it < niter; ++it) {
        int qd = it * TPB + tid;
        float4 A = p4[3 * qd + 0], Bv = p4[3 * qd + 1], C = p4[3 * qd + 2];
        push_pt(A.x,  A.y,  A.z,  k, lane, q, qn, A64, B64);
        push_pt(A.w,  Bv.x, Bv.y, k, lane, q, qn, A64, B64);
        push_pt(Bv.z, Bv.w, C.x,  k, lane, q, qn, A64, B64);
        push_pt(C.y,  C.z,  C.w,  k, lane, q, qn, A64, B64);
    }
    // tail drain (qn in [0,63], wave-uniform)
    if (lane < qn) heavy(q[lane], k, A64, B64);
    __syncthreads();

    // decode: cell (pl, iy, iz) = A[tile(iy,iz)] + B[tile(iy-1,iz-1)]
    const unsigned short* a16 = (const unsigned short*)A64;
    const unsigned short* b16 = (const unsigned short*)B64;
    float* ob = out + (size_t)b * G3 + (size_t)(TH * k) * G2;
    for (int t = tid; t < TH * G2; t += TPB) {
        int pl = t >> 12;
        int cell = t & 4095;
        int iy = cell >> 6, iz = cell & 63;
        unsigned v = a16[(pl << 12) +
                         (((iy >> 1) * 32 + (iz >> 1)) << 2) +
                         ((iy & 1) << 1) + (iz & 1)];
        if (iy > 0 && iz > 0) {
            v += b16[(pl << 12) +
                     ((((iy - 1) >> 1) * 32 + ((iz - 1) >> 1)) << 2) +
                     (((iy - 1) & 1) << 1) + ((iz - 1) & 1)];
        }
        ob[t] = (float)v * QDEC;
    }
}

// ---- fallback (general shapes): R1 atomic kernel ----
__global__ void gridding_atomic_kernel(const float* __restrict__ pt,
                                       float* __restrict__ out, int P, int N) {
    int i = blockIdx.x * blockDim.x + threadIdx.x;
    if (i >= P) return;
    int b = i / N;
    float x = pt[3 * i + 0] * (float)SHALF;
    float y = pt[3 * i + 1] * (float)SHALF;
    float z = pt[3 * i + 2] * (float)SHALF;
    const float m = ((x + y + z) != 0.0f) ? 1.0f : 0.0f;
    float lx = floorf(x), ly = floorf(y), lz = floorf(z);
    float fx = x - lx, fy = y - ly, fz = z - lz;
    int ix = min(max((int)lx + SHALF, 0), GS - 2);
    int iy = min(max((int)ly + SHALF, 0), GS - 2);
    int iz = min(max((int)lz + SHALF, 0), GS - 2);
    float* base = out + (size_t)b * G3 + ((ix * GS + iy) * GS + iz);
    float wx0 = (1.0f - fx) * m, wx1 = fx * m;
    float w00 = wx0 * (1.0f - fy), w01 = wx0 * fy;
    float w10 = wx1 * (1.0f - fy), w11 = wx1 * fy;
    atomicAdd(base,               w00 * (1.0f - fz));
    atomicAdd(base + 1,           w00 * fz);
    atomicAdd(base + GS,          w01 * (1.0f - fz));
    atomicAdd(base + GS + 1,      w01 * fz);
    atomicAdd(base + G2,          w10 * (1.0f - fz));
    atomicAdd(base + G2 + 1,      w10 * fz);
    atomicAdd(base + G2 + GS,     w11 * (1.0f - fz));
    atomicAdd(base + G2 + GS + 1, w11 * fz);
}

extern "C" void kernel_launch(void* const* d_in, const int* in_sizes, int n_in,
                              void* d_out, int out_size, void* d_ws, size_t ws_size,
                              hipStream_t stream) {
    const float* pt  = (const float*)d_in[0];
    float*       out = (float*)d_out;

    const int P = in_sizes[0] / 3;       // total points (B*N)
    const int B = out_size / G3;         // 32
    const int N = (B > 0) ? P / B : 0;   // 262144

    const bool fast = (B > 0) && (out_size == B * G3) && (P == B * N) &&
                      (N % (4 * TPB) == 0);

    if (fast) {
        dim3 g(B, NSLAB);                // 256 wgs = 1/CU
        gridding_u16_kernel<<<g, TPB, 0, stream>>>(pt, out, N);
    } else {
        hipMemsetAsync(d_out, 0, (size_t)out_size * sizeof(float), stream);
        gridding_atomic_kernel<<<(P + 255) / 256, 256, 0, stream>>>(pt, out, P, N);
    }
}